// Round 2
// 5008.371 us; speedup vs baseline: 4.4776x; 4.4776x over previous
//
#include <hip/hip_runtime.h>
#include <hip/hip_bf16.h>
#include <stdint.h>

#define B_   128
#define S_   512
#define C_   256
#define DG_  256

// d_out offsets (fp32 elements): outs, pi, sigma, mu, mask
#define OFF_PI   262144
#define OFF_SIG  917504
#define OFF_MU   3538944
#define OFF_MASK 6160384

typedef __hip_bfloat16 bf16;
typedef __bf16 bf16x8 __attribute__((ext_vector_type(8)));
typedef float  f32x4  __attribute__((ext_vector_type(4)));
typedef unsigned int u32;

// ---- staging in device globals (zero d_ws dependence) ----
__device__ __align__(16) bf16  gWmain[768*256];   // Wih0[:, :256]
__device__ __align__(16) bf16  gWHH0 [768*256];
__device__ __align__(16) bf16  gWIH1 [768*256];
__device__ __align__(16) bf16  gWHH1 [768*256];
__device__ __align__(16) bf16  gWcat [96*512];    // [W_pi; W_sigma; W_mu; 0]
__device__ __align__(16) float gWtail[768*4];     // Wih0[:, 256:260] fp32
__device__ __align__(16) float gSm   [3200];      // small params fp32
__device__ __align__(16) bf16  gHbuf [B_*S_*DG_]; // h1 per (b,t), b-major (32 MB)
__device__ __align__(16) bf16  gH0   [B_*S_*DG_]; // h0 per (t,b), t-major (32 MB)
__device__ __align__(16) float gGi0  [50331648];  // gi0[t][b][768] fp32 (201 MB)
__device__ __align__(16) float gGi1  [50331648];  // gi1[t][b][768] fp32 (201 MB)
__device__ __align__(16) float gPn   [65536*4];   // prenet per (b,t)

// gSm offsets
#define SM_WPRE 0
#define SM_BPRE 16
#define SM_BIH0 20
#define SM_BHH0 788
#define SM_BIH1 1556
#define SM_BHH1 2324
#define SM_BPI  3092
#define SM_BSIG 3102
#define SM_BMU  3142

__device__ __forceinline__ bf16  f2b(float x){ return __float2bfloat16(x); }
__device__ __forceinline__ unsigned short b2u(bf16 x){
    union { bf16 b; unsigned short u; } c; c.b = x; return c.u;
}
__device__ __forceinline__ float sigm(float x){ return 1.f/(1.f + __expf(-x)); }
__device__ __forceinline__ float tanhfast(float x){ return 1.f - 2.f/(__expf(2.f*x) + 1.f); }
__device__ __forceinline__ f32x4 mfma16(bf16x8 a, bf16x8 b, f32x4 c){
    return __builtin_amdgcn_mfma_f32_16x16x32_bf16(a, b, c, 0, 0, 0);
}
__device__ __forceinline__ bf16x8 cvt8(const float* f){
    float4 a = *reinterpret_cast<const float4*>(f);
    float4 c = *reinterpret_cast<const float4*>(f + 4);
    bf16 o[8] = { f2b(a.x),f2b(a.y),f2b(a.z),f2b(a.w),
                  f2b(c.x),f2b(c.y),f2b(c.z),f2b(c.w) };
    return *reinterpret_cast<bf16x8*>(o);
}

// ---------------------------------------------------------------------------
// ingest: canonicalize fp32 params into device globals + prenet
#define IN_N0 199680
#define IN_N1 396288
#define IN_N2 592896
#define IN_N3 789504
#define IN_N4 838656
#define IN_N5 841838
#define IN_N6 1103982
__global__ __launch_bounds__(256) void k_ingest(
    const float* __restrict__ Wih0, const float* __restrict__ Whh0,
    const float* __restrict__ Wih1, const float* __restrict__ Whh1,
    const float* __restrict__ Wpi, const float* __restrict__ Wsig,
    const float* __restrict__ Wmu,
    const float* __restrict__ Wpre, const float* __restrict__ bpre,
    const float* __restrict__ bih0, const float* __restrict__ bhh0,
    const float* __restrict__ bih1, const float* __restrict__ bhh1,
    const float* __restrict__ bpi, const float* __restrict__ bsig,
    const float* __restrict__ bmu, const float* __restrict__ tgt)
{
    int j = blockIdx.x*256 + threadIdx.x;
    if (j < IN_N0){
        int r = j/260, c = j - r*260;
        float v = Wih0[j];
        if (c < 256) gWmain[r*256 + c] = f2b(v);
        else         gWtail[r*4 + (c-256)] = v;
    } else if (j < IN_N1){
        int k = j - IN_N0; gWHH0[k] = f2b(Whh0[k]);
    } else if (j < IN_N2){
        int k = j - IN_N1; gWIH1[k] = f2b(Wih1[k]);
    } else if (j < IN_N3){
        int k = j - IN_N2; gWHH1[k] = f2b(Whh1[k]);
    } else if (j < IN_N4){
        int k = j - IN_N3; int r = k >> 9, c = k & 511;
        float v = 0.f;
        if      (r < 10) v = Wpi[r*512 + c];
        else if (r < 50) v = Wsig[(r-10)*512 + c];
        else if (r < 90) v = Wmu[(r-50)*512 + c];
        gWcat[k] = f2b(v);
    } else if (j < IN_N5){
        int k = j - IN_N4;
        float v;
        if      (k < 16)   v = Wpre[k];
        else if (k < 20)   v = bpre[k-16];
        else if (k < 788)  v = bih0[k-20];
        else if (k < 1556) v = bhh0[k-788];
        else if (k < 2324) v = bih1[k-1556];
        else if (k < 3092) v = bhh1[k-2324];
        else if (k < 3102) v = bpi[k-3092];
        else if (k < 3142) v = bsig[k-3102];
        else               v = bmu[k-3142];
        gSm[k] = v;
    } else if (j < IN_N6){
        // prenet: pn[m][jj] = bpre[jj] + sum_q Wpre[jj][q]*tgt[m-1][q]  (m = b*512+t)
        int k = j - IN_N5, m = k>>2, jj = k&3, tq = m&511;
        float acc = bpre[jj];
        if (tq){
            const float* pv = tgt + (size_t)(m-1)*4;
            #pragma unroll
            for (int q=0;q<4;q++) acc += Wpre[jj*4+q]*pv[q];
        }
        gPn[m*4+jj] = acc;
    }
}

// ---------------------------------------------------------------------------
// k_gi0: gi0[t][b][n] = (Wih0 @ [enc;prenet])[n] + bih0[n], all (b,t).
// 1024 blocks x 256 thr; block = 64 M-rows (m = b*512+t), full N=768.
__global__ __launch_bounds__(256) void k_gi0(const float* __restrict__ enc)
{
    const int tid = threadIdx.x, w = tid>>6, lane = tid&63;
    const int col = lane&15, quad = lane>>4;
    const int m0 = blockIdx.x*64 + w*16;

    bf16x8 aF[8];
    #pragma unroll
    for (int kt=0; kt<8; kt++)
        aF[kt] = cvt8(enc + (size_t)(m0+col)*256 + kt*32 + quad*8);

    float4 pnr[4];
    #pragma unroll
    for (int r=0; r<4; r++)
        pnr[r] = *reinterpret_cast<const float4*>(gPn + (size_t)(m0 + quad*4 + r)*4);
    const int mrow = m0 + quad*4;

    for (int nt=0; nt<48; nt++){
        const int n = nt*16 + col;
        f32x4 acc = {0.f,0.f,0.f,0.f};
        #pragma unroll
        for (int kt=0; kt<8; kt++){
            bf16x8 bW = *reinterpret_cast<const bf16x8*>(gWmain + (size_t)n*256 + kt*32 + quad*8);
            acc = mfma16(aF[kt], bW, acc);
        }
        float4 wt = ((const float4*)gWtail)[n];
        float  bi = gSm[SM_BIH0 + n];
        #pragma unroll
        for (int r=0; r<4; r++){
            int m = mrow + r; int bq = m>>9, tq = m&511;
            float v = acc[r] + bi + wt.x*pnr[r].x + wt.y*pnr[r].y
                              + wt.z*pnr[r].z + wt.w*pnr[r].w;
            gGi0[((size_t)tq*128 + bq)*768 + n] = v;
        }
    }
}

// ---------------------------------------------------------------------------
// k_gi1: gi1[t][b][n] = (Wih1 @ h0[t][b])[n] + bih1[n]. h0 is t-major bf16.
// m = t*128 + b. 1024 blocks x 256 thr.
__global__ __launch_bounds__(256) void k_gi1()
{
    const int tid = threadIdx.x, w = tid>>6, lane = tid&63;
    const int col = lane&15, quad = lane>>4;
    const int m0 = blockIdx.x*64 + w*16;

    bf16x8 aF[8];
    #pragma unroll
    for (int kt=0; kt<8; kt++)
        aF[kt] = *reinterpret_cast<const bf16x8*>(gH0 + (size_t)(m0+col)*256 + kt*32 + quad*8);

    for (int nt=0; nt<48; nt++){
        const int n = nt*16 + col;
        f32x4 acc = {0.f,0.f,0.f,0.f};
        #pragma unroll
        for (int kt=0; kt<8; kt++){
            bf16x8 bW = *reinterpret_cast<const bf16x8*>(gWIH1 + (size_t)n*256 + kt*32 + quad*8);
            acc = mfma16(aF[kt], bW, acc);
        }
        float bi = gSm[SM_BIH1 + n];
        #pragma unroll
        for (int r=0; r<4; r++)
            gGi1[((size_t)(m0 + quad*4 + r))*768 + n] = acc[r] + bi;
    }
}

// ---------------------------------------------------------------------------
// k_rec: single-layer sequential ZoneOut-GRU half. 32 blocks x 512 thr
// (8 waves), block = 4 batches, all 256 dims local (NO inter-block comms).
// Whh: 48 row-tiles; 4/wave VGPR-resident (128 VGPR), 2/wave streamed from
// L2 each step (hot: 384 KB << 4 MB/XCD). gi(t) stream prefetched into regs.
// layer=0: gi=gGi0, W=gWHH0, hout=gH0 (t-major). layer=1: gGi1/gWHH1/gHbuf (b-major).
__global__ __launch_bounds__(512, 2) void k_rec(int layer)
{
    __shared__ bf16  hv[4][264];      // bf16 h(t-1), 4 batches x 256
    __shared__ float gA[3][4][264];   // gh MFMA results
    __shared__ float bhL[3][256];     // bhh

    const bf16*  __restrict__ W  = layer ? gWHH1 : gWHH0;
    const float* __restrict__ gi = layer ? gGi1  : gGi0;
    const int smOff = layer ? SM_BHH1 : SM_BHH0;
    bf16* __restrict__ hout = layer ? gHbuf : gH0;

    const int tid = threadIdx.x, w = tid>>6, lane = tid&63;
    const int col = lane&15, quad = lane>>4;
    const int bg4 = blockIdx.x*4;
    const int gb = tid>>7, dp = tid&127;   // gate thread: batch, dim-pair

    for (int i=tid; i<4*264; i+=512) (&hv[0][0])[i] = f2b(0.f);
    for (int i=tid; i<768;  i+=512) bhL[i>>8][i&255] = gSm[smOff + i];

    // resident weight fragments: wave w tiles v = w*6 + j, j=0..3
    bf16x8 wf[4][8];
    #pragma unroll
    for (int j=0;j<4;j++){
        int v = w*6+j, g = v>>4, q = v&15;
        const bf16* Wr = W + ((size_t)(g*256 + q*16 + col))*256;
        #pragma unroll
        for (int kt=0;kt<8;kt++)
            wf[j][kt] = *reinterpret_cast<const bf16x8*>(Wr + kt*32 + quad*8);
    }
    // streamed tiles j=4,5: row base pointers
    const bf16* Ws0; const bf16* Ws1;
    { int v = w*6+4;
      Ws0 = W + ((size_t)((v>>4)*256 + (v&15)*16 + col))*256;
      v = w*6+5;
      Ws1 = W + ((size_t)((v>>4)*256 + (v&15)*16 + col))*256; }

    // gi stream: per-thread base (batch bg4+gb, dims dp*2..dp*2+1)
    const float* gip = gi + ((size_t)(bg4+gb))*768 + dp*2;
    float2 gc[3], gn[3];
    #pragma unroll
    for (int g=0;g<3;g++) gc[g] = *reinterpret_cast<const float2*>(gip + g*256);

    float hreg[2] = {0.f, 0.f};       // fp32 h for this thread's 2 dims

    __syncthreads();

    #pragma unroll 1
    for (int t=0; t<S_; t++){
        // --- issue stream tile s0 + gi(t+1) prefetch ---
        bf16x8 s0[8];
        #pragma unroll
        for (int kt=0;kt<8;kt++)
            s0[kt] = *reinterpret_cast<const bf16x8*>(Ws0 + kt*32 + quad*8);
        if (t+1 < S_){
            const float* gq = gip + (size_t)(t+1)*98304;   // 128*768
            #pragma unroll
            for (int g=0;g<3;g++) gn[g] = *reinterpret_cast<const float2*>(gq + g*256);
        }
        // --- h fragments from LDS ---
        bf16x8 hb[8];
        #pragma unroll
        for (int kt=0;kt<8;kt++)
            hb[kt] = *reinterpret_cast<const bf16x8*>(&hv[col&3][kt*32 + quad*8]);
        // --- resident tiles ---
        #pragma unroll
        for (int j=0;j<4;j++){
            f32x4 a = {0.f,0.f,0.f,0.f};
            #pragma unroll
            for (int kt=0;kt<8;kt++) a = mfma16(wf[j][kt], hb[kt], a);
            int v = w*6+j, g = v>>4, q = v&15;
            if (col < 4){
                #pragma unroll
                for (int r=0;r<4;r++) gA[g][col][q*16 + quad*4 + r] = a[r];
            }
        }
        // --- streamed tile s0 ---
        {
            f32x4 a = {0.f,0.f,0.f,0.f};
            #pragma unroll
            for (int kt=0;kt<8;kt++) a = mfma16(s0[kt], hb[kt], a);
            int v = w*6+4, g = v>>4, q = v&15;
            if (col < 4){
                #pragma unroll
                for (int r=0;r<4;r++) gA[g][col][q*16 + quad*4 + r] = a[r];
            }
        }
        // --- streamed tile s1 ---
        {
            bf16x8 s1[8];
            #pragma unroll
            for (int kt=0;kt<8;kt++)
                s1[kt] = *reinterpret_cast<const bf16x8*>(Ws1 + kt*32 + quad*8);
            f32x4 a = {0.f,0.f,0.f,0.f};
            #pragma unroll
            for (int kt=0;kt<8;kt++) a = mfma16(s1[kt], hb[kt], a);
            int v = w*6+5, g = v>>4, q = v&15;
            if (col < 4){
                #pragma unroll
                for (int r=0;r<4;r++) gA[g][col][q*16 + quad*4 + r] = a[r];
            }
        }
        __syncthreads();                    // gA ready

        // --- gates: thread = (gb, dims dp*2..dp*2+1) ---
        {
            float hp2[2];
            #pragma unroll
            for (int e=0;e<2;e++){
                int d = dp*2 + e;
                float ir  = e ? gc[0].y : gc[0].x;
                float iz  = e ? gc[1].y : gc[1].x;
                float inn = e ? gc[2].y : gc[2].x;
                float hr = gA[0][gb][d] + bhL[0][d];
                float hz = gA[1][gb][d] + bhL[1][d];
                float hn = gA[2][gb][d] + bhL[2][d];
                float r = sigm(ir + hr), z = sigm(iz + hz);
                float n = tanhfast(inn + r*hn);
                float h = hreg[e];
                float hp = 0.1f*h + 0.9f*((1.f - z)*n + z*h);
                hreg[e] = hp; hp2[e] = hp;
            }
            u32 u = (u32)b2u(f2b(hp2[0])) | ((u32)b2u(f2b(hp2[1]))<<16);
            *reinterpret_cast<u32*>(&hv[gb][dp*2]) = u;
            size_t ho = layer
                ? (((size_t)(bg4+gb)*S_ + t)*256 + dp*2)     // b-major (gHbuf)
                : (((size_t)t*128 + (bg4+gb))*256 + dp*2);   // t-major (gH0)
            *reinterpret_cast<u32*>(hout + ho) = u;
        }
        __syncthreads();                    // hv(t) ready for next step
        #pragma unroll
        for (int g=0;g<3;g++) gc[g] = gn[g];
    }
}

// ---------------------------------------------------------------------------
// Fused projection + heads: 512 blocks x 128 rows. [H|enc]@Wcat^T -> LDS ->
// softmax/elu/mu, fp32 stores.
__global__ __launch_bounds__(256) void k_proj(
    const float* __restrict__ enc, float* __restrict__ dout)
{
    __shared__ float st[128][100];
    const int tid = threadIdx.x, w = tid>>6, lane = tid&63;
    const int col = lane&15, quad = lane>>4;
    const int Mb = blockIdx.x*128;
    const int M0 = Mb + w*32;

    f32x4 acc[2][6];
    #pragma unroll
    for (int mt=0; mt<2; mt++)
        #pragma unroll
        for (int nt=0; nt<6; nt++) acc[mt][nt] = f32x4{0.f,0.f,0.f,0.f};

    #pragma unroll
    for (int kt=0; kt<16; kt++){
        bf16x8 a0, a1;
        if (kt < 8){
            a0 = *reinterpret_cast<const bf16x8*>(gHbuf + (size_t)(M0 +      col)*DG_ + kt*32 + quad*8);
            a1 = *reinterpret_cast<const bf16x8*>(gHbuf + (size_t)(M0 + 16 + col)*DG_ + kt*32 + quad*8);
        } else {
            a0 = cvt8(enc + (size_t)(M0 +      col)*C_ + (kt-8)*32 + quad*8);
            a1 = cvt8(enc + (size_t)(M0 + 16 + col)*C_ + (kt-8)*32 + quad*8);
        }
        #pragma unroll
        for (int nt=0; nt<6; nt++){
            bf16x8 b = *reinterpret_cast<const bf16x8*>(gWcat + (size_t)(nt*16 + col)*512 + kt*32 + quad*8);
            acc[0][nt] = mfma16(a0, b, acc[0][nt]);
            acc[1][nt] = mfma16(a1, b, acc[1][nt]);
        }
    }
    #pragma unroll
    for (int nt=0; nt<6; nt++)
        #pragma unroll
        for (int mt=0; mt<2; mt++)
            #pragma unroll
            for (int r=0; r<4; r++)
                st[w*32 + mt*16 + quad*4 + r][nt*16 + col] = acc[mt][nt][r];
    __syncthreads();

    if (tid < 128){
        const float* v = st[tid];
        const size_t m = (size_t)Mb + tid;
        float x[10], mx = -1e30f;
        #pragma unroll
        for (int g=0; g<10; g++){ x[g] = v[g] + gSm[SM_BPI+g]; mx = fmaxf(mx, x[g]); }
        float sum = 0.f;
        #pragma unroll
        for (int g=0; g<10; g++){ x[g] = __expf(x[g]-mx); sum += x[g]; }
        float inv = 1.f/sum;
        #pragma unroll
        for (int g=0; g<10; g++)
            dout[OFF_PI + m*10 + g] = x[g]*inv;
        #pragma unroll
        for (int i=0; i<40; i++){
            float s = v[10+i] + gSm[SM_BSIG+i];
            dout[OFF_SIG + m*40 + i] = (s > 0.f) ? (s + 1.f) : __expf(s);
        }
        #pragma unroll
        for (int i=0; i<40; i++)
            dout[OFF_MU + m*40 + i] = v[50+i] + gSm[SM_BMU+i];
    }
}

// ---------------------------------------------------------------------------
// blocks 0..255: outs = fp32 copy of tgt; blocks 256..383: mask
__global__ __launch_bounds__(256) void k_misc(const float* __restrict__ tgt,
    const int* __restrict__ dur, float* __restrict__ dout)
{
    if (blockIdx.x < 256){
        int i = blockIdx.x*256 + threadIdx.x;
        ((float4*)dout)[i] = ((const float4*)tgt)[i];
    } else {
        __shared__ int red[256];
        int b = blockIdx.x - 256;
        int c = 0;
        for (int s = threadIdx.x; s < S_; s += 256) c += (dur[b*S_ + s] > 0) ? 1 : 0;
        red[threadIdx.x] = c;
        __syncthreads();
        for (int off=128; off>0; off>>=1){
            if (threadIdx.x < off) red[threadIdx.x] += red[threadIdx.x+off];
            __syncthreads();
        }
        int snt = red[0];
        for (int s = threadIdx.x; s < S_; s += 256)
            dout[OFF_MASK + (size_t)b*S_ + s] = (s >= snt) ? 1.f : 0.f;
    }
}

// ---------------------------------------------------------------------------
extern "C" void kernel_launch(void* const* d_in, const int* in_sizes, int n_in,
                              void* d_out, int out_size, void* d_ws, size_t ws_size,
                              hipStream_t stream)
{
    (void)d_ws; (void)ws_size;
    const float* enc  = (const float*)d_in[0];
    const float* tgt  = (const float*)d_in[1];
    const int*   dur  = (const int*)  d_in[2];
    const float* Wpre = (const float*)d_in[3];
    const float* bpre = (const float*)d_in[4];
    const float* Wih0 = (const float*)d_in[5];
    const float* Whh0 = (const float*)d_in[6];
    const float* bih0 = (const float*)d_in[7];
    const float* bhh0 = (const float*)d_in[8];
    const float* Wih1 = (const float*)d_in[9];
    const float* Whh1 = (const float*)d_in[10];
    const float* bih1 = (const float*)d_in[11];
    const float* bhh1 = (const float*)d_in[12];
    const float* Wpi  = (const float*)d_in[13];
    const float* bpi  = (const float*)d_in[14];
    const float* Wsig = (const float*)d_in[15];
    const float* bsig = (const float*)d_in[16];
    const float* Wmu  = (const float*)d_in[17];
    const float* bmu  = (const float*)d_in[18];
    float* dout = (float*)d_out;

    hipLaunchKernelGGL(k_ingest, dim3(4313), dim3(256), 0, stream,
                       Wih0, Whh0, Wih1, Whh1, Wpi, Wsig, Wmu,
                       Wpre, bpre, bih0, bhh0, bih1, bhh1, bpi, bsig, bmu, tgt);
    hipLaunchKernelGGL(k_gi0,  dim3(1024), dim3(256), 0, stream, enc);
    hipLaunchKernelGGL(k_rec,  dim3(32),   dim3(512), 0, stream, 0);
    hipLaunchKernelGGL(k_gi1,  dim3(1024), dim3(256), 0, stream);
    hipLaunchKernelGGL(k_rec,  dim3(32),   dim3(512), 0, stream, 1);
    hipLaunchKernelGGL(k_proj, dim3(512),  dim3(256), 0, stream, enc, dout);
    hipLaunchKernelGGL(k_misc, dim3(384),  dim3(256), 0, stream, tgt, dur, dout);
}

// Round 3
// 2273.864 us; speedup vs baseline: 9.8624x; 2.2026x over previous
//
#include <hip/hip_runtime.h>
#include <hip/hip_bf16.h>
#include <stdint.h>

#define B_   128
#define S_   512
#define C_   256
#define DG_  256

// d_out offsets (fp32 elements): outs, pi, sigma, mu, mask
#define OFF_PI   262144
#define OFF_SIG  917504
#define OFF_MU   3538944
#define OFF_MASK 6160384

typedef __hip_bfloat16 bf16;
typedef __bf16 bf16x8 __attribute__((ext_vector_type(8)));
typedef float  f32x4  __attribute__((ext_vector_type(4)));
typedef unsigned int u32;
typedef unsigned int u32x4 __attribute__((ext_vector_type(4)));

// ---- staging in device globals (zero d_ws dependence) ----
__device__ __align__(16) bf16  gWmain[768*256];   // Wih0[:, :256]
__device__ __align__(16) bf16  gWHH0 [768*256];
__device__ __align__(16) bf16  gWIH1 [768*256];
__device__ __align__(16) bf16  gWHH1 [768*256];
__device__ __align__(16) bf16  gWcat [96*512];    // [W_pi; W_sigma; W_mu; 0]
__device__ __align__(16) float gWtail[768*4];     // Wih0[:, 256:260] fp32
__device__ __align__(16) float gSm   [3200];      // small params fp32
__device__ __align__(16) bf16  gHbuf [B_*S_*DG_]; // h1 per (b,t), b-major (32 MB)
__device__ __align__(16) bf16  gH0   [B_*S_*DG_]; // h0 per (t,b), t-major (32 MB)
__device__ __align__(16) float gGi0  [50331648];  // gi0[t][b][768] fp32 (201 MB)
__device__ __align__(16) float gGi1  [50331648];  // gi1[t][b][768] fp32 (201 MB)
__device__ __align__(16) float gPn   [65536*4];   // prenet per (b,t)

// gSm offsets
#define SM_WPRE 0
#define SM_BPRE 16
#define SM_BIH0 20
#define SM_BHH0 788
#define SM_BIH1 1556
#define SM_BHH1 2324
#define SM_BPI  3092
#define SM_BSIG 3102
#define SM_BMU  3142

__device__ __forceinline__ bf16  f2b(float x){ return __float2bfloat16(x); }
__device__ __forceinline__ unsigned short b2u(bf16 x){
    union { bf16 b; unsigned short u; } c; c.b = x; return c.u;
}
__device__ __forceinline__ float sigm(float x){ return 1.f/(1.f + __expf(-x)); }
__device__ __forceinline__ float tanhfast(float x){ return 1.f - 2.f/(__expf(2.f*x) + 1.f); }
__device__ __forceinline__ f32x4 mfma16(bf16x8 a, bf16x8 b, f32x4 c){
    return __builtin_amdgcn_mfma_f32_16x16x32_bf16(a, b, c, 0, 0, 0);
}
__device__ __forceinline__ bf16x8 u2b(u32x4 x){
    union { u32x4 u; bf16x8 b; } c; c.u = x; return c.b;
}
__device__ __forceinline__ bf16x8 cvt8(const float* f){
    float4 a = *reinterpret_cast<const float4*>(f);
    float4 c = *reinterpret_cast<const float4*>(f + 4);
    bf16 o[8] = { f2b(a.x),f2b(a.y),f2b(a.z),f2b(a.w),
                  f2b(c.x),f2b(c.y),f2b(c.z),f2b(c.w) };
    return *reinterpret_cast<bf16x8*>(o);
}

// ---------------------------------------------------------------------------
// ingest: canonicalize fp32 params into device globals + prenet
#define IN_N0 199680
#define IN_N1 396288
#define IN_N2 592896
#define IN_N3 789504
#define IN_N4 838656
#define IN_N5 841838
#define IN_N6 1103982
__global__ __launch_bounds__(256) void k_ingest(
    const float* __restrict__ Wih0, const float* __restrict__ Whh0,
    const float* __restrict__ Wih1, const float* __restrict__ Whh1,
    const float* __restrict__ Wpi, const float* __restrict__ Wsig,
    const float* __restrict__ Wmu,
    const float* __restrict__ Wpre, const float* __restrict__ bpre,
    const float* __restrict__ bih0, const float* __restrict__ bhh0,
    const float* __restrict__ bih1, const float* __restrict__ bhh1,
    const float* __restrict__ bpi, const float* __restrict__ bsig,
    const float* __restrict__ bmu, const float* __restrict__ tgt)
{
    int j = blockIdx.x*256 + threadIdx.x;
    if (j < IN_N0){
        int r = j/260, c = j - r*260;
        float v = Wih0[j];
        if (c < 256) gWmain[r*256 + c] = f2b(v);
        else         gWtail[r*4 + (c-256)] = v;
    } else if (j < IN_N1){
        int k = j - IN_N0; gWHH0[k] = f2b(Whh0[k]);
    } else if (j < IN_N2){
        int k = j - IN_N1; gWIH1[k] = f2b(Wih1[k]);
    } else if (j < IN_N3){
        int k = j - IN_N2; gWHH1[k] = f2b(Whh1[k]);
    } else if (j < IN_N4){
        int k = j - IN_N3; int r = k >> 9, c = k & 511;
        float v = 0.f;
        if      (r < 10) v = Wpi[r*512 + c];
        else if (r < 50) v = Wsig[(r-10)*512 + c];
        else if (r < 90) v = Wmu[(r-50)*512 + c];
        gWcat[k] = f2b(v);
    } else if (j < IN_N5){
        int k = j - IN_N4;
        float v;
        if      (k < 16)   v = Wpre[k];
        else if (k < 20)   v = bpre[k-16];
        else if (k < 788)  v = bih0[k-20];
        else if (k < 1556) v = bhh0[k-788];
        else if (k < 2324) v = bih1[k-1556];
        else if (k < 3092) v = bhh1[k-2324];
        else if (k < 3102) v = bpi[k-3092];
        else if (k < 3142) v = bsig[k-3102];
        else               v = bmu[k-3142];
        gSm[k] = v;
    } else if (j < IN_N6){
        // prenet: pn[m][jj] = bpre[jj] + sum_q Wpre[jj][q]*tgt[m-1][q]  (m = b*512+t)
        int k = j - IN_N5, m = k>>2, jj = k&3, tq = m&511;
        float acc = bpre[jj];
        if (tq){
            const float* pv = tgt + (size_t)(m-1)*4;
            #pragma unroll
            for (int q=0;q<4;q++) acc += Wpre[jj*4+q]*pv[q];
        }
        gPn[m*4+jj] = acc;
    }
}

// ---------------------------------------------------------------------------
// k_gi0: gi0[t][b][n] = (Wih0 @ [enc;prenet])[n] + bih0[n], all (b,t).
// 1024 blocks x 256 thr; block = 64 M-rows (m = b*512+t), full N=768.
__global__ __launch_bounds__(256) void k_gi0(const float* __restrict__ enc)
{
    const int tid = threadIdx.x, w = tid>>6, lane = tid&63;
    const int col = lane&15, quad = lane>>4;
    const int m0 = blockIdx.x*64 + w*16;

    bf16x8 aF[8];
    #pragma unroll
    for (int kt=0; kt<8; kt++)
        aF[kt] = cvt8(enc + (size_t)(m0+col)*256 + kt*32 + quad*8);

    float4 pnr[4];
    #pragma unroll
    for (int r=0; r<4; r++)
        pnr[r] = *reinterpret_cast<const float4*>(gPn + (size_t)(m0 + quad*4 + r)*4);
    const int mrow = m0 + quad*4;

    for (int nt=0; nt<48; nt++){
        const int n = nt*16 + col;
        f32x4 acc = {0.f,0.f,0.f,0.f};
        #pragma unroll
        for (int kt=0; kt<8; kt++){
            bf16x8 bW = *reinterpret_cast<const bf16x8*>(gWmain + (size_t)n*256 + kt*32 + quad*8);
            acc = mfma16(aF[kt], bW, acc);
        }
        float4 wt = ((const float4*)gWtail)[n];
        float  bi = gSm[SM_BIH0 + n];
        #pragma unroll
        for (int r=0; r<4; r++){
            int m = mrow + r; int bq = m>>9, tq = m&511;
            float v = acc[r] + bi + wt.x*pnr[r].x + wt.y*pnr[r].y
                              + wt.z*pnr[r].z + wt.w*pnr[r].w;
            gGi0[((size_t)tq*128 + bq)*768 + n] = v;
        }
    }
}

// ---------------------------------------------------------------------------
// k_gi1: gi1[t][b][n] = (Wih1 @ h0[t][b])[n] + bih1[n]. h0 is t-major bf16.
// m = t*128 + b. 1024 blocks x 256 thr.
__global__ __launch_bounds__(256) void k_gi1()
{
    const int tid = threadIdx.x, w = tid>>6, lane = tid&63;
    const int col = lane&15, quad = lane>>4;
    const int m0 = blockIdx.x*64 + w*16;

    bf16x8 aF[8];
    #pragma unroll
    for (int kt=0; kt<8; kt++)
        aF[kt] = *reinterpret_cast<const bf16x8*>(gH0 + (size_t)(m0+col)*256 + kt*32 + quad*8);

    for (int nt=0; nt<48; nt++){
        const int n = nt*16 + col;
        f32x4 acc = {0.f,0.f,0.f,0.f};
        #pragma unroll
        for (int kt=0; kt<8; kt++){
            bf16x8 bW = *reinterpret_cast<const bf16x8*>(gWIH1 + (size_t)n*256 + kt*32 + quad*8);
            acc = mfma16(aF[kt], bW, acc);
        }
        float bi = gSm[SM_BIH1 + n];
        #pragma unroll
        for (int r=0; r<4; r++)
            gGi1[((size_t)(m0 + quad*4 + r))*768 + n] = acc[r] + bi;
    }
}

// ---------------------------------------------------------------------------
// k_rec: single-layer sequential ZoneOut-GRU half. 32 blocks x 512 thr
// (8 waves), block = 4 batches, all 256 dims local (NO inter-block comms).
// Whh: 48 row-tiles; per wave 6 tiles: 4 PINNED in VGPRs (asm keep-live so
// the compiler cannot rematerialize = re-fetch from L2 per step; that remat
// was the R2 bottleneck: 384KB/step @ ~56B/cyc = ~7k cyc of the 10.4k step),
// 2 staged once into LDS (16 tiles = 128 KB) and ds_read per step.
__global__ __launch_bounds__(512, 2) void k_rec(int layer)
{
    __shared__ bf16  sW[16][8][64][8];  // 128 KB: 16 streamed tiles
    __shared__ bf16  hv[4][264];        // bf16 h(t-1), 4 batches x 256
    __shared__ float gA[3][4][264];     // gh MFMA results
    __shared__ float bhL[3][256];       // bhh

    const bf16*  __restrict__ W  = layer ? gWHH1 : gWHH0;
    const float* __restrict__ gi = layer ? gGi1  : gGi0;
    const int smOff = layer ? SM_BHH1 : SM_BHH0;
    bf16* __restrict__ hout = layer ? gHbuf : gH0;

    const int tid = threadIdx.x, w = tid>>6, lane = tid&63;
    const int col = lane&15, quad = lane>>4;
    const int bg4 = blockIdx.x*4;
    const int gb = tid>>7, dp = tid&127;   // gate thread: batch, dim-pair

    for (int i=tid; i<4*264; i+=512) (&hv[0][0])[i] = f2b(0.f);
    for (int i=tid; i<768;  i+=512) bhL[i>>8][i&255] = gSm[smOff + i];

    // ---- resident weight fragments, PINNED: wave w tiles v = w*6+j, j=0..3
    u32x4 wf[4][8];
    #pragma unroll
    for (int j=0;j<4;j++){
        int v = w*6+j, g = v>>4, q = v&15;
        const bf16* Wr = W + ((size_t)(g*256 + q*16 + col))*256;
        #pragma unroll
        for (int kt=0;kt<8;kt++){
            wf[j][kt] = *reinterpret_cast<const u32x4*>(Wr + kt*32 + quad*8);
            asm volatile("" : "+v"(wf[j][kt]));   // opaque: no remat, stay in VGPR
        }
    }
    // ---- stage tiles j=4,5 into LDS (once) ----
    #pragma unroll
    for (int ti=0; ti<2; ti++){
        int v = w*6+4+ti, g = v>>4, q = v&15;
        const bf16* Wr = W + ((size_t)(g*256 + q*16 + col))*256;
        #pragma unroll
        for (int kt=0;kt<8;kt++)
            *reinterpret_cast<bf16x8*>(&sW[w*2+ti][kt][lane][0]) =
                *reinterpret_cast<const bf16x8*>(Wr + kt*32 + quad*8);
    }

    // gi stream: per-thread base (batch bg4+gb, dims dp*2..dp*2+1)
    const float* gip = gi + ((size_t)(bg4+gb))*768 + dp*2;
    float2 gc[3], gn[3];
    #pragma unroll
    for (int g=0;g<3;g++) gc[g] = *reinterpret_cast<const float2*>(gip + g*256);

    float hreg[2] = {0.f, 0.f};       // fp32 h for this thread's 2 dims

    __syncthreads();

    #pragma unroll 1
    for (int t=0; t<S_; t++){
        // --- gi(t+1) prefetch (covered by MFMA phase before barrier drain) ---
        if (t+1 < S_){
            const float* gq = gip + (size_t)(t+1)*98304;   // 128*768
            #pragma unroll
            for (int g=0;g<3;g++) gn[g] = *reinterpret_cast<const float2*>(gq + g*256);
        }
        // --- h fragments from LDS ---
        bf16x8 hb[8];
        #pragma unroll
        for (int kt=0;kt<8;kt++)
            hb[kt] = *reinterpret_cast<const bf16x8*>(&hv[col&3][kt*32 + quad*8]);
        // --- 4 pinned VGPR tiles ---
        #pragma unroll
        for (int j=0;j<4;j++){
            f32x4 a = {0.f,0.f,0.f,0.f};
            #pragma unroll
            for (int kt=0;kt<8;kt++) a = mfma16(u2b(wf[j][kt]), hb[kt], a);
            int v = w*6+j, g = v>>4, q = v&15;
            if (col < 4){
                #pragma unroll
                for (int r=0;r<4;r++) gA[g][col][q*16 + quad*4 + r] = a[r];
            }
        }
        // --- 2 LDS tiles ---
        #pragma unroll
        for (int ti=0; ti<2; ti++){
            f32x4 a = {0.f,0.f,0.f,0.f};
            #pragma unroll
            for (int kt=0;kt<8;kt++){
                bf16x8 s = *reinterpret_cast<const bf16x8*>(&sW[w*2+ti][kt][lane][0]);
                a = mfma16(s, hb[kt], a);
            }
            int v = w*6+4+ti, g = v>>4, q = v&15;
            if (col < 4){
                #pragma unroll
                for (int r=0;r<4;r++) gA[g][col][q*16 + quad*4 + r] = a[r];
            }
        }
        __syncthreads();                    // gA ready

        // --- gates: thread = (gb, dims dp*2..dp*2+1) ---
        {
            float hp2[2];
            #pragma unroll
            for (int e=0;e<2;e++){
                int d = dp*2 + e;
                float ir  = e ? gc[0].y : gc[0].x;
                float iz  = e ? gc[1].y : gc[1].x;
                float inn = e ? gc[2].y : gc[2].x;
                float hr = gA[0][gb][d] + bhL[0][d];
                float hz = gA[1][gb][d] + bhL[1][d];
                float hn = gA[2][gb][d] + bhL[2][d];
                float r = sigm(ir + hr), z = sigm(iz + hz);
                float n = tanhfast(inn + r*hn);
                float h = hreg[e];
                float hp = 0.1f*h + 0.9f*((1.f - z)*n + z*h);
                hreg[e] = hp; hp2[e] = hp;
            }
            u32 u = (u32)b2u(f2b(hp2[0])) | ((u32)b2u(f2b(hp2[1]))<<16);
            *reinterpret_cast<u32*>(&hv[gb][dp*2]) = u;
            size_t ho = layer
                ? (((size_t)(bg4+gb)*S_ + t)*256 + dp*2)     // b-major (gHbuf)
                : (((size_t)t*128 + (bg4+gb))*256 + dp*2);   // t-major (gH0)
            *reinterpret_cast<u32*>(hout + ho) = u;
        }
        __syncthreads();                    // hv(t) ready for next step
        #pragma unroll
        for (int g=0;g<3;g++) gc[g] = gn[g];
    }
}

// ---------------------------------------------------------------------------
// Fused projection + heads: 512 blocks x 128 rows. [H|enc]@Wcat^T -> LDS ->
// softmax/elu/mu, fp32 stores.
__global__ __launch_bounds__(256) void k_proj(
    const float* __restrict__ enc, float* __restrict__ dout)
{
    __shared__ float st[128][100];
    const int tid = threadIdx.x, w = tid>>6, lane = tid&63;
    const int col = lane&15, quad = lane>>4;
    const int Mb = blockIdx.x*128;
    const int M0 = Mb + w*32;

    f32x4 acc[2][6];
    #pragma unroll
    for (int mt=0; mt<2; mt++)
        #pragma unroll
        for (int nt=0; nt<6; nt++) acc[mt][nt] = f32x4{0.f,0.f,0.f,0.f};

    #pragma unroll
    for (int kt=0; kt<16; kt++){
        bf16x8 a0, a1;
        if (kt < 8){
            a0 = *reinterpret_cast<const bf16x8*>(gHbuf + (size_t)(M0 +      col)*DG_ + kt*32 + quad*8);
            a1 = *reinterpret_cast<const bf16x8*>(gHbuf + (size_t)(M0 + 16 + col)*DG_ + kt*32 + quad*8);
        } else {
            a0 = cvt8(enc + (size_t)(M0 +      col)*C_ + (kt-8)*32 + quad*8);
            a1 = cvt8(enc + (size_t)(M0 + 16 + col)*C_ + (kt-8)*32 + quad*8);
        }
        #pragma unroll
        for (int nt=0; nt<6; nt++){
            bf16x8 b = *reinterpret_cast<const bf16x8*>(gWcat + (size_t)(nt*16 + col)*512 + kt*32 + quad*8);
            acc[0][nt] = mfma16(a0, b, acc[0][nt]);
            acc[1][nt] = mfma16(a1, b, acc[1][nt]);
        }
    }
    #pragma unroll
    for (int nt=0; nt<6; nt++)
        #pragma unroll
        for (int mt=0; mt<2; mt++)
            #pragma unroll
            for (int r=0; r<4; r++)
                st[w*32 + mt*16 + quad*4 + r][nt*16 + col] = acc[mt][nt][r];
    __syncthreads();

    if (tid < 128){
        const float* v = st[tid];
        const size_t m = (size_t)Mb + tid;
        float x[10], mx = -1e30f;
        #pragma unroll
        for (int g=0; g<10; g++){ x[g] = v[g] + gSm[SM_BPI+g]; mx = fmaxf(mx, x[g]); }
        float sum = 0.f;
        #pragma unroll
        for (int g=0; g<10; g++){ x[g] = __expf(x[g]-mx); sum += x[g]; }
        float inv = 1.f/sum;
        #pragma unroll
        for (int g=0; g<10; g++)
            dout[OFF_PI + m*10 + g] = x[g]*inv;
        #pragma unroll
        for (int i=0; i<40; i++){
            float s = v[10+i] + gSm[SM_BSIG+i];
            dout[OFF_SIG + m*40 + i] = (s > 0.f) ? (s + 1.f) : __expf(s);
        }
        #pragma unroll
        for (int i=0; i<40; i++)
            dout[OFF_MU + m*40 + i] = v[50+i] + gSm[SM_BMU+i];
    }
}

// ---------------------------------------------------------------------------
// blocks 0..255: outs = fp32 copy of tgt; blocks 256..383: mask
__global__ __launch_bounds__(256) void k_misc(const float* __restrict__ tgt,
    const int* __restrict__ dur, float* __restrict__ dout)
{
    if (blockIdx.x < 256){
        int i = blockIdx.x*256 + threadIdx.x;
        ((float4*)dout)[i] = ((const float4*)tgt)[i];
    } else {
        __shared__ int red[256];
        int b = blockIdx.x - 256;
        int c = 0;
        for (int s = threadIdx.x; s < S_; s += 256) c += (dur[b*S_ + s] > 0) ? 1 : 0;
        red[threadIdx.x] = c;
        __syncthreads();
        for (int off=128; off>0; off>>=1){
            if (threadIdx.x < off) red[threadIdx.x] += red[threadIdx.x+off];
            __syncthreads();
        }
        int snt = red[0];
        for (int s = threadIdx.x; s < S_; s += 256)
            dout[OFF_MASK + (size_t)b*S_ + s] = (s >= snt) ? 1.f : 0.f;
    }
}

// ---------------------------------------------------------------------------
extern "C" void kernel_launch(void* const* d_in, const int* in_sizes, int n_in,
                              void* d_out, int out_size, void* d_ws, size_t ws_size,
                              hipStream_t stream)
{
    (void)d_ws; (void)ws_size;
    const float* enc  = (const float*)d_in[0];
    const float* tgt  = (const float*)d_in[1];
    const int*   dur  = (const int*)  d_in[2];
    const float* Wpre = (const float*)d_in[3];
    const float* bpre = (const float*)d_in[4];
    const float* Wih0 = (const float*)d_in[5];
    const float* Whh0 = (const float*)d_in[6];
    const float* bih0 = (const float*)d_in[7];
    const float* bhh0 = (const float*)d_in[8];
    const float* Wih1 = (const float*)d_in[9];
    const float* Whh1 = (const float*)d_in[10];
    const float* bih1 = (const float*)d_in[11];
    const float* bhh1 = (const float*)d_in[12];
    const float* Wpi  = (const float*)d_in[13];
    const float* bpi  = (const float*)d_in[14];
    const float* Wsig = (const float*)d_in[15];
    const float* bsig = (const float*)d_in[16];
    const float* Wmu  = (const float*)d_in[17];
    const float* bmu  = (const float*)d_in[18];
    float* dout = (float*)d_out;

    hipLaunchKernelGGL(k_ingest, dim3(4313), dim3(256), 0, stream,
                       Wih0, Whh0, Wih1, Whh1, Wpi, Wsig, Wmu,
                       Wpre, bpre, bih0, bhh0, bih1, bhh1, bpi, bsig, bmu, tgt);
    hipLaunchKernelGGL(k_gi0,  dim3(1024), dim3(256), 0, stream, enc);
    hipLaunchKernelGGL(k_rec,  dim3(32),   dim3(512), 0, stream, 0);
    hipLaunchKernelGGL(k_gi1,  dim3(1024), dim3(256), 0, stream);
    hipLaunchKernelGGL(k_rec,  dim3(32),   dim3(512), 0, stream, 1);
    hipLaunchKernelGGL(k_proj, dim3(512),  dim3(256), 0, stream, enc, dout);
    hipLaunchKernelGGL(k_misc, dim3(384),  dim3(256), 0, stream, tgt, dur, dout);
}